// Round 1
// baseline (713.059 us; speedup 1.0000x reference)
//
#include <hip/hip_runtime.h>
#include <hip/hip_bf16.h>

// GCN 2-layer: deg -> isd -> CSR build -> GEMM1 -> agg1(+b1,relu) -> GEMM2 -> agg2(+b2)
// All fp32. CSR rebuilt every call (harness re-poisons ws).

#define N_NODES 100000

// ---------------- degree histogram ----------------
__global__ void k_deg(const int* __restrict__ dst, int* __restrict__ deg, int E) {
    int e = blockIdx.x * blockDim.x + threadIdx.x;
    if (e < E) atomicAdd(&deg[dst[e]], 1);
}

// ---------------- isd + offset allocation (wave-scan + one atomic/wave) ----------------
__global__ void k_isd_offsets(const int* __restrict__ deg, float* __restrict__ isd,
                              int* __restrict__ offsets, int* __restrict__ counter, int N) {
    int n = blockIdx.x * blockDim.x + threadIdx.x;
    int lane = threadIdx.x & 63;
    int d = (n < N) ? deg[n] : 0;
    if (n < N) isd[n] = (d > 0) ? rsqrtf((float)d) : 0.f;
    // inclusive wave scan of d
    int pref = d;
    #pragma unroll
    for (int sh = 1; sh < 64; sh <<= 1) {
        int t = __shfl_up(pref, sh);
        if (lane >= sh) pref += t;
    }
    int total = __shfl(pref, 63);
    int base = 0;
    if (lane == 63) base = atomicAdd(counter, total);
    base = __shfl(base, 63);
    if (n < N) offsets[n] = base + pref - d;  // exclusive within this wave's range
}

// ---------------- CSR scatter ----------------
__global__ void k_scatter(const int* __restrict__ src, const int* __restrict__ dst,
                          const float* __restrict__ isd, const int* __restrict__ offsets,
                          int* __restrict__ cursor, int* __restrict__ csr_src,
                          float* __restrict__ csr_w, int E) {
    int e = blockIdx.x * blockDim.x + threadIdx.x;
    if (e >= E) return;
    int d = dst[e];
    int s = src[e];
    int pos = atomicAdd(&cursor[d], 1);
    int i = offsets[d] + pos;
    csr_src[i] = s;
    csr_w[i] = isd[s] * isd[d];
}

// ---------------- GEMM1: h[N,128] = x[N,256] @ W1[256,128] ----------------
// BM=64 BN=128 BK=16, 256 threads, thread tile 8x4
__global__ __launch_bounds__(256) void k_gemm1(const float* __restrict__ X,
                                               const float* __restrict__ W,
                                               float* __restrict__ H, int N) {
    __shared__ float sA[16][64];   // [k][m]
    __shared__ float sB[16][128];  // [k][n]
    int tid = threadIdx.x;
    int block_row = blockIdx.x * 64;
    int tx = tid & 31;   // col group: 4 cols each
    int ty = tid >> 5;   // row group: 8 rows each
    float acc[8][4] = {};

    for (int k0 = 0; k0 < 256; k0 += 16) {
        // load A tile: 64 rows x 16 k, float4 along k, transpose into sA[k][m]
        {
            int r = tid >> 2;            // 0..63
            int kk = (tid & 3) << 2;     // 0,4,8,12
            int grow = block_row + r;
            float4 v = make_float4(0.f, 0.f, 0.f, 0.f);
            if (grow < N) v = *(const float4*)&X[(size_t)grow * 256 + k0 + kk];
            sA[kk + 0][r] = v.x; sA[kk + 1][r] = v.y;
            sA[kk + 2][r] = v.z; sA[kk + 3][r] = v.w;
        }
        // load B tile: 16 k x 128 cols
        {
            int c = (tid & 31) << 2;     // 0..124
            int kk = tid >> 5;           // 0..7
            *(float4*)&sB[kk][c]     = *(const float4*)&W[(size_t)(k0 + kk) * 128 + c];
            *(float4*)&sB[kk + 8][c] = *(const float4*)&W[(size_t)(k0 + kk + 8) * 128 + c];
        }
        __syncthreads();
        #pragma unroll
        for (int k = 0; k < 16; ++k) {
            float4 a0 = *(const float4*)&sA[k][ty * 8];
            float4 a1 = *(const float4*)&sA[k][ty * 8 + 4];
            float4 bv = *(const float4*)&sB[k][tx * 4];
            float a[8] = {a0.x, a0.y, a0.z, a0.w, a1.x, a1.y, a1.z, a1.w};
            float b[4] = {bv.x, bv.y, bv.z, bv.w};
            #pragma unroll
            for (int i = 0; i < 8; ++i)
                #pragma unroll
                for (int j = 0; j < 4; ++j)
                    acc[i][j] = fmaf(a[i], b[j], acc[i][j]);
        }
        __syncthreads();
    }
    #pragma unroll
    for (int i = 0; i < 8; ++i) {
        int r = block_row + ty * 8 + i;
        if (r < N) {
            *(float4*)&H[(size_t)r * 128 + tx * 4] =
                make_float4(acc[i][0], acc[i][1], acc[i][2], acc[i][3]);
        }
    }
}

// ---------------- agg1: h1[n][c] = relu(b1[c] + sum_e w*h[src][c]) , C=128 ----------------
// one wave per node; cooperative edge staging + shfl broadcast
__global__ __launch_bounds__(256) void k_agg1(const float* __restrict__ H,
                                              const int* __restrict__ csr_src,
                                              const float* __restrict__ csr_w,
                                              const int* __restrict__ offsets,
                                              const int* __restrict__ deg,
                                              const float* __restrict__ b1,
                                              float* __restrict__ H1, int N) {
    int wave = (blockIdx.x * blockDim.x + threadIdx.x) >> 6;
    int lane = threadIdx.x & 63;
    if (wave >= N) return;
    int start = offsets[wave];
    int cnt = deg[wave];
    float acc0 = 0.f, acc1 = 0.f;
    for (int i0 = 0; i0 < cnt; i0 += 64) {
        int m = min(64, cnt - i0);
        int s_l = 0; float w_l = 0.f;
        if (lane < m) {
            s_l = csr_src[start + i0 + lane];
            w_l = csr_w[start + i0 + lane];
        }
        for (int i = 0; i < m; ++i) {
            int s = __shfl(s_l, i);
            float w = __shfl(w_l, i);
            const float* hp = &H[(size_t)s * 128];
            acc0 = fmaf(w, hp[lane], acc0);
            acc1 = fmaf(w, hp[lane + 64], acc1);
        }
    }
    float r0 = acc0 + b1[lane];
    float r1 = acc1 + b1[lane + 64];
    H1[(size_t)wave * 128 + lane] = fmaxf(r0, 0.f);
    H1[(size_t)wave * 128 + lane + 64] = fmaxf(r1, 0.f);
}

// ---------------- GEMM2: h2[N,40] = h1[N,128] @ W2[128,40] ----------------
__global__ __launch_bounds__(256) void k_gemm2(const float* __restrict__ H1,
                                               const float* __restrict__ W2,
                                               float* __restrict__ H2, int N) {
    __shared__ float sH[64][132];    // +4 pad to break stride-128 bank conflicts
    __shared__ float sW[128 * 40];
    int tid = threadIdx.x;
    int block_row = blockIdx.x * 64;
    // stage H1 tile
    for (int i = tid; i < 64 * 32; i += 256) {
        int r = i >> 5;
        int c4 = (i & 31) << 2;
        int grow = block_row + r;
        float4 v = make_float4(0.f, 0.f, 0.f, 0.f);
        if (grow < N) v = *(const float4*)&H1[(size_t)grow * 128 + c4];
        sH[r][c4 + 0] = v.x; sH[r][c4 + 1] = v.y;
        sH[r][c4 + 2] = v.z; sH[r][c4 + 3] = v.w;
    }
    // stage W2
    for (int i = tid; i < 1280; i += 256) {
        *(float4*)&sW[i * 4] = *(const float4*)&W2[(size_t)i * 4];
    }
    __syncthreads();

    int row = tid >> 2;          // 0..63
    int c0 = (tid & 3) * 10;     // 0,10,20,30
    float acc[10] = {};
    for (int k = 0; k < 128; ++k) {
        float hv = sH[row][k];
        #pragma unroll
        for (int j = 0; j < 5; ++j) {
            float2 wv = *(const float2*)&sW[k * 40 + c0 + 2 * j];
            acc[2 * j]     = fmaf(hv, wv.x, acc[2 * j]);
            acc[2 * j + 1] = fmaf(hv, wv.y, acc[2 * j + 1]);
        }
    }
    int grow = block_row + row;
    if (grow < N) {
        #pragma unroll
        for (int j = 0; j < 5; ++j) {
            *(float2*)&H2[(size_t)grow * 40 + c0 + 2 * j] =
                make_float2(acc[2 * j], acc[2 * j + 1]);
        }
    }
}

// ---------------- agg2: out[n][c] = b2[c] + sum_e w*h2[src][c] , C=40 ----------------
__global__ __launch_bounds__(256) void k_agg2(const float* __restrict__ H2,
                                              const int* __restrict__ csr_src,
                                              const float* __restrict__ csr_w,
                                              const int* __restrict__ offsets,
                                              const int* __restrict__ deg,
                                              const float* __restrict__ b2,
                                              float* __restrict__ out, int N) {
    int wave = (blockIdx.x * blockDim.x + threadIdx.x) >> 6;
    int lane = threadIdx.x & 63;
    if (wave >= N) return;
    int start = offsets[wave];
    int cnt = deg[wave];
    float acc = 0.f;
    for (int i0 = 0; i0 < cnt; i0 += 64) {
        int m = min(64, cnt - i0);
        int s_l = 0; float w_l = 0.f;
        if (lane < m) {
            s_l = csr_src[start + i0 + lane];
            w_l = csr_w[start + i0 + lane];
        }
        for (int i = 0; i < m; ++i) {
            int s = __shfl(s_l, i);
            float w = __shfl(w_l, i);
            // lanes >= 40 read junk in-bounds of the h buffer; never stored
            acc = fmaf(w, H2[(size_t)s * 40 + (lane < 40 ? lane : 0)], acc);
        }
    }
    if (lane < 40) out[(size_t)wave * 40 + lane] = acc + b2[lane];
}

extern "C" void kernel_launch(void* const* d_in, const int* in_sizes, int n_in,
                              void* d_out, int out_size, void* d_ws, size_t ws_size,
                              hipStream_t stream) {
    const float* x  = (const float*)d_in[0];
    const int*  src = (const int*)d_in[1];
    const int*  dst = (const int*)d_in[2];
    const float* W1 = (const float*)d_in[3];
    const float* b1 = (const float*)d_in[4];
    const float* W2 = (const float*)d_in[5];
    const float* b2 = (const float*)d_in[6];
    float* out = (float*)d_out;

    const int N = in_sizes[0] / 256;   // 100000
    const int E = in_sizes[1];         // 1600000

    // ---- workspace layout (16B-aligned regions) ----
    char* w = (char*)d_ws;
    auto alloc = [&](size_t bytes) -> void* {
        void* p = (void*)w;
        w += (bytes + 15) & ~(size_t)15;
        return p;
    };
    int*   deg     = (int*)alloc((size_t)N * 4);      // zeroed
    int*   cursor  = (int*)alloc((size_t)N * 4);      // zeroed
    int*   counter = (int*)alloc(16);                 // zeroed
    float* isd     = (float*)alloc((size_t)N * 4);
    int*   offsets = (int*)alloc((size_t)N * 4);
    int*   csr_src = (int*)alloc((size_t)E * 4);
    float* csr_w   = (float*)alloc((size_t)E * 4);
    float* h       = (float*)alloc((size_t)N * 128 * 4);
    float* h1      = (float*)alloc((size_t)N * 128 * 4);
    float* h2      = h;   // h dead after agg1; reuse for h2 [N,40]

    // zero deg + cursor + counter (contiguous: N*4 is 16B-multiple)
    hipMemsetAsync(deg, 0, (size_t)N * 4 * 2 + 16, stream);

    k_deg<<<(E + 255) / 256, 256, 0, stream>>>(dst, deg, E);
    k_isd_offsets<<<(N + 255) / 256, 256, 0, stream>>>(deg, isd, offsets, counter, N);
    k_scatter<<<(E + 255) / 256, 256, 0, stream>>>(src, dst, isd, offsets, cursor,
                                                   csr_src, csr_w, E);
    k_gemm1<<<(N + 63) / 64, 256, 0, stream>>>(x, W1, h, N);
    k_agg1<<<(N + 3) / 4, 256, 0, stream>>>(h, csr_src, csr_w, offsets, deg, b1, h1, N);
    k_gemm2<<<(N + 63) / 64, 256, 0, stream>>>(h1, W2, h2, N);
    k_agg2<<<(N + 3) / 4, 256, 0, stream>>>(h2, csr_src, csr_w, offsets, deg, b2, out, N);
}

// Round 2
// 638.218 us; speedup vs baseline: 1.1173x; 1.1173x over previous
//
#include <hip/hip_runtime.h>
#include <hip/hip_bf16.h>

// GCN 2-layer: deg -> isd -> CSR -> prep_w1 -> GEMM1(bf16 MFMA) -> agg1(+b1,relu)
//              -> GEMM2 -> agg2(+b2). Intermediates h/h1/h2 in bf16.

typedef __bf16 bf16x8 __attribute__((ext_vector_type(8)));
typedef float floatx4 __attribute__((ext_vector_type(4)));

__device__ inline unsigned short f2bf(float f) {      // RNE fp32->bf16
    unsigned u = __float_as_uint(f);
    u += 0x7FFF + ((u >> 16) & 1);
    return (unsigned short)(u >> 16);
}
__device__ inline float bflo(unsigned p) { return __uint_as_float(p << 16); }
__device__ inline float bfhi(unsigned p) { return __uint_as_float(p & 0xFFFF0000u); }

// ---------------- degree histogram ----------------
__global__ void k_deg(const int* __restrict__ dst, int* __restrict__ deg, int E) {
    int e = blockIdx.x * blockDim.x + threadIdx.x;
    if (e < E) atomicAdd(&deg[dst[e]], 1);
}

// ---------------- isd + offsets (wave scan + 1 atomic/wave) ----------------
__global__ void k_isd_offsets(const int* __restrict__ deg, float* __restrict__ isd,
                              int* __restrict__ offsets, int* __restrict__ counter, int N) {
    int n = blockIdx.x * blockDim.x + threadIdx.x;
    int lane = threadIdx.x & 63;
    int d = (n < N) ? deg[n] : 0;
    if (n < N) isd[n] = (d > 0) ? rsqrtf((float)d) : 0.f;
    int pref = d;
    #pragma unroll
    for (int sh = 1; sh < 64; sh <<= 1) {
        int t = __shfl_up(pref, sh);
        if (lane >= sh) pref += t;
    }
    int total = __shfl(pref, 63);
    int base = 0;
    if (lane == 63) base = atomicAdd(counter, total);
    base = __shfl(base, 63);
    if (n < N) offsets[n] = base + pref - d;
}

// ---------------- CSR scatter ----------------
__global__ void k_scatter(const int* __restrict__ src, const int* __restrict__ dst,
                          const float* __restrict__ isd, const int* __restrict__ offsets,
                          int* __restrict__ cursor, int* __restrict__ csr_src,
                          float* __restrict__ csr_w, int E) {
    int e = blockIdx.x * blockDim.x + threadIdx.x;
    if (e >= E) return;
    int d = dst[e];
    int s = src[e];
    int pos = atomicAdd(&cursor[d], 1);
    int i = offsets[d] + pos;
    csr_src[i] = s;
    csr_w[i] = isd[s] * isd[d];
}

// ---------------- W1 -> bf16, MFMA B-fragment order ----------------
// layout: ((kt*8 + nt)*64 + lane)*8 + j ; element = W1[(kt*32+(lane>>4)*8+j)*128 + nt*16+(lane&15)]
__global__ void k_prep_w1(const float* __restrict__ W1, unsigned short* __restrict__ w1s) {
    int flat = blockIdx.x * 256 + threadIdx.x;   // 0..4095
    int kt = flat >> 9;
    int nt = (flat >> 6) & 7;
    int lane = flat & 63;
    int kbase = kt * 32 + ((lane >> 4) << 3);
    int n = nt * 16 + (lane & 15);
    unsigned short v[8];
    #pragma unroll
    for (int j = 0; j < 8; ++j) v[j] = f2bf(W1[(size_t)(kbase + j) * 128 + n]);
    unsigned short* d = &w1s[(size_t)flat * 8];
    *(short4*)(d)     = make_short4(v[0], v[1], v[2], v[3]);
    *(short4*)(d + 4) = make_short4(v[4], v[5], v[6], v[7]);
}

// ---------------- GEMM1: h[N,128](bf16) = x[N,256] @ W1 , MFMA 16x16x32 ----------------
// 256 thr = 4 waves in 2x2; block tile 64x128; wave tile 32x64; BK=32, 8 k-steps
__global__ __launch_bounds__(256) void k_gemm1(const float* __restrict__ X,
                                               const unsigned short* __restrict__ w1s,
                                               unsigned short* __restrict__ H, int N) {
    __shared__ __align__(16) unsigned short smem[8192];  // 16KB: loop uses 12KB, epilogue 16KB
    unsigned short* sA = smem;            // 4 mt * 64 lanes * 8 = 2048
    unsigned short* sB = smem + 2048;     // 8 nt * 64 lanes * 8 = 4096
    int tid = threadIdx.x;
    int lane = tid & 63;
    int wave = tid >> 6;
    int wr = wave >> 1;                   // m-offset wr*32
    int wc = wave & 1;                    // n-offset wc*64
    int m0 = blockIdx.x * 64;

    floatx4 acc[2][4] = {};

    for (int kt = 0; kt < 8; ++kt) {
        // stage A: 64 rows x 32 k, fp32 -> bf16, fragment order
        #pragma unroll
        for (int i = 0; i < 2; ++i) {
            int f = tid * 2 + i;          // 0..511
            int row = f >> 3;             // 0..63
            int c4 = (f & 7) * 4;         // 0,4,...,28
            float4 v = make_float4(0.f, 0.f, 0.f, 0.f);
            int grow = m0 + row;
            if (grow < N) v = *(const float4*)&X[(size_t)grow * 256 + kt * 32 + c4];
            int mt = row >> 4;
            int flane = (row & 15) | ((c4 >> 3) << 4);
            int j0 = c4 & 7;              // 0 or 4
            unsigned short* d = &sA[(size_t)(mt * 64 + flane) * 8 + j0];
            *(short4*)d = make_short4(f2bf(v.x), f2bf(v.y), f2bf(v.z), f2bf(v.w));
        }
        // stage B: 8KB contiguous (pre-swizzled)
        {
            const float4* srcp = (const float4*)&w1s[(size_t)kt * 4096];
            float4* dstp = (float4*)sB;
            dstp[tid] = srcp[tid];
            dstp[tid + 256] = srcp[tid + 256];
        }
        __syncthreads();
        bf16x8 a[2], b[4];
        #pragma unroll
        for (int p = 0; p < 2; ++p)
            a[p] = *(const bf16x8*)&sA[(size_t)((wr * 2 + p) * 64 + lane) * 8];
        #pragma unroll
        for (int q = 0; q < 4; ++q)
            b[q] = *(const bf16x8*)&sB[(size_t)((wc * 4 + q) * 64 + lane) * 8];
        #pragma unroll
        for (int p = 0; p < 2; ++p)
            #pragma unroll
            for (int q = 0; q < 4; ++q)
                acc[p][q] = __builtin_amdgcn_mfma_f32_16x16x32_bf16(a[p], b[q], acc[p][q], 0, 0, 0);
        __syncthreads();
    }
    // epilogue: C frags -> LDS bf16 tile -> coalesced global
    #pragma unroll
    for (int p = 0; p < 2; ++p)
        #pragma unroll
        for (int q = 0; q < 4; ++q)
            #pragma unroll
            for (int r = 0; r < 4; ++r) {
                int rl = wr * 32 + p * 16 + ((lane >> 4) << 2) + r;
                int c = wc * 64 + q * 16 + (lane & 15);
                smem[rl * 128 + c] = f2bf(acc[p][q][r]);
            }
    __syncthreads();
    #pragma unroll
    for (int i = 0; i < 4; ++i) {
        int f = tid + i * 256;            // 0..1023
        int row = f >> 4;
        int c8 = (f & 15) * 8;
        int grow = m0 + row;
        if (grow < N)
            *(float4*)&H[(size_t)grow * 128 + c8] = *(const float4*)&smem[row * 128 + c8];
    }
}

// ---------------- agg1: h1(bf16) = relu(b1 + sum w*h[src]) , C=128 ----------------
// one wave/node; lane l owns channels (2l, 2l+1); 1x 4B bf16x2 load per edge per lane
__global__ __launch_bounds__(256) void k_agg1(const unsigned short* __restrict__ H,
                                              const int* __restrict__ csr_src,
                                              const float* __restrict__ csr_w,
                                              const int* __restrict__ offsets,
                                              const int* __restrict__ deg,
                                              const float* __restrict__ b1,
                                              unsigned short* __restrict__ H1, int N) {
    int node = (blockIdx.x * blockDim.x + threadIdx.x) >> 6;
    int lane = threadIdx.x & 63;
    if (node >= N) return;
    int start = offsets[node];
    int cnt = deg[node];
    const unsigned* Hu = (const unsigned*)H;
    float acc0 = 0.f, acc1 = 0.f;
    for (int i0 = 0; i0 < cnt; i0 += 64) {
        int m = min(64, cnt - i0);
        int s_l = 0; float w_l = 0.f;
        if (lane < m) {
            s_l = csr_src[start + i0 + lane];
            w_l = csr_w[start + i0 + lane];
        }
        for (int i = 0; i < m; ++i) {
            int s = __shfl(s_l, i);
            float w = __shfl(w_l, i);
            unsigned p = Hu[(size_t)s * 64 + lane];
            acc0 = fmaf(w, bflo(p), acc0);
            acc1 = fmaf(w, bfhi(p), acc1);
        }
    }
    float r0 = fmaxf(acc0 + b1[2 * lane], 0.f);
    float r1 = fmaxf(acc1 + b1[2 * lane + 1], 0.f);
    ((unsigned*)H1)[(size_t)node * 64 + lane] = (unsigned)f2bf(r0) | ((unsigned)f2bf(r1) << 16);
}

// ---------------- GEMM2: h2[N,40](bf16) = h1(bf16) @ W2[128,40] ----------------
__global__ __launch_bounds__(256) void k_gemm2(const unsigned short* __restrict__ H1,
                                               const float* __restrict__ W2,
                                               unsigned short* __restrict__ H2, int N) {
    __shared__ float sH[64][132];
    __shared__ float sW[128 * 40];
    int tid = threadIdx.x;
    int block_row = blockIdx.x * 64;
    for (int i = tid; i < 64 * 16; i += 256) {
        int r = i >> 4;
        int c8 = (i & 15) * 8;
        int grow = block_row + r;
        uint4 v = make_uint4(0, 0, 0, 0);
        if (grow < N) v = *(const uint4*)&H1[(size_t)grow * 128 + c8];
        float* d = &sH[r][c8];
        d[0] = bflo(v.x); d[1] = bfhi(v.x);
        d[2] = bflo(v.y); d[3] = bfhi(v.y);
        d[4] = bflo(v.z); d[5] = bfhi(v.z);
        d[6] = bflo(v.w); d[7] = bfhi(v.w);
    }
    for (int i = tid; i < 1280; i += 256)
        *(float4*)&sW[i * 4] = *(const float4*)&W2[(size_t)i * 4];
    __syncthreads();

    int row = tid >> 2;
    int c0 = (tid & 3) * 10;
    float acc[10] = {};
    for (int k = 0; k < 128; ++k) {
        float hv = sH[row][k];
        #pragma unroll
        for (int j = 0; j < 5; ++j) {
            float2 wv = *(const float2*)&sW[k * 40 + c0 + 2 * j];
            acc[2 * j]     = fmaf(hv, wv.x, acc[2 * j]);
            acc[2 * j + 1] = fmaf(hv, wv.y, acc[2 * j + 1]);
        }
    }
    int grow = block_row + row;
    if (grow < N) {
        unsigned* o = (unsigned*)&H2[(size_t)grow * 40 + c0];
        #pragma unroll
        for (int j = 0; j < 5; ++j)
            o[j] = (unsigned)f2bf(acc[2 * j]) | ((unsigned)f2bf(acc[2 * j + 1]) << 16);
    }
}

// ---------------- agg2: out[n][c](fp32) = b2 + sum w*h2[src] , C=40 ----------------
__global__ __launch_bounds__(256) void k_agg2(const unsigned short* __restrict__ H2,
                                              const int* __restrict__ csr_src,
                                              const float* __restrict__ csr_w,
                                              const int* __restrict__ offsets,
                                              const int* __restrict__ deg,
                                              const float* __restrict__ b2,
                                              float* __restrict__ out, int N) {
    int node = (blockIdx.x * blockDim.x + threadIdx.x) >> 6;
    int lane = threadIdx.x & 63;
    if (node >= N) return;
    int start = offsets[node];
    int cnt = deg[node];
    const unsigned* Hu = (const unsigned*)H2;
    float acc0 = 0.f, acc1 = 0.f;
    for (int i0 = 0; i0 < cnt; i0 += 64) {
        int m = min(64, cnt - i0);
        int s_l = 0; float w_l = 0.f;
        if (lane < m) {
            s_l = csr_src[start + i0 + lane];
            w_l = csr_w[start + i0 + lane];
        }
        for (int i = 0; i < m; ++i) {
            int s = __shfl(s_l, i);
            float w = __shfl(w_l, i);
            if (lane < 20) {
                unsigned p = Hu[(size_t)s * 20 + lane];
                acc0 = fmaf(w, bflo(p), acc0);
                acc1 = fmaf(w, bfhi(p), acc1);
            }
        }
    }
    if (lane < 20)
        *(float2*)&out[(size_t)node * 40 + 2 * lane] =
            make_float2(acc0 + b2[2 * lane], acc1 + b2[2 * lane + 1]);
}

extern "C" void kernel_launch(void* const* d_in, const int* in_sizes, int n_in,
                              void* d_out, int out_size, void* d_ws, size_t ws_size,
                              hipStream_t stream) {
    const float* x  = (const float*)d_in[0];
    const int*  src = (const int*)d_in[1];
    const int*  dst = (const int*)d_in[2];
    const float* W1 = (const float*)d_in[3];
    const float* b1 = (const float*)d_in[4];
    const float* W2 = (const float*)d_in[5];
    const float* b2 = (const float*)d_in[6];
    float* out = (float*)d_out;

    const int N = in_sizes[0] / 256;   // 100000
    const int E = in_sizes[1];         // 1600000

    char* w = (char*)d_ws;
    auto alloc = [&](size_t bytes) -> void* {
        void* p = (void*)w;
        w += (bytes + 15) & ~(size_t)15;
        return p;
    };
    int*   deg     = (int*)alloc((size_t)N * 4);      // zeroed below
    int*   cursor  = (int*)alloc((size_t)N * 4);      // zeroed below
    int*   counter = (int*)alloc(16);                 // zeroed below
    float* isd     = (float*)alloc((size_t)N * 4);
    int*   offsets = (int*)alloc((size_t)N * 4);
    int*   csr_src = (int*)alloc((size_t)E * 4);
    float* csr_w   = (float*)alloc((size_t)E * 4);
    unsigned short* w1s = (unsigned short*)alloc(32768 * 2);
    unsigned short* h   = (unsigned short*)alloc((size_t)N * 128 * 2);
    unsigned short* h1  = (unsigned short*)alloc((size_t)N * 128 * 2);
    unsigned short* h2  = h;   // h dead after agg1

    hipMemsetAsync(deg, 0, (size_t)N * 4 * 2 + 16, stream);

    k_deg<<<(E + 255) / 256, 256, 0, stream>>>(dst, deg, E);
    k_isd_offsets<<<(N + 255) / 256, 256, 0, stream>>>(deg, isd, offsets, counter, N);
    k_scatter<<<(E + 255) / 256, 256, 0, stream>>>(src, dst, isd, offsets, cursor,
                                                   csr_src, csr_w, E);
    k_prep_w1<<<16, 256, 0, stream>>>(W1, w1s);
    k_gemm1<<<(N + 63) / 64, 256, 0, stream>>>(x, w1s, h, N);
    k_agg1<<<(N + 3) / 4, 256, 0, stream>>>(h, csr_src, csr_w, offsets, deg, b1, h1, N);
    k_gemm2<<<(N + 63) / 64, 256, 0, stream>>>(h1, W2, h2, N);
    k_agg2<<<(N + 3) / 4, 256, 0, stream>>>(h2, csr_src, csr_w, offsets, deg, b2, out, N);
}

// Round 3
// 542.980 us; speedup vs baseline: 1.3132x; 1.1754x over previous
//
#include <hip/hip_runtime.h>
#include <hip/hip_bf16.h>

// GCN 2-layer: deg -> isd -> CSR(int2) -> prep_w1 -> GEMM1(bf16 MFMA) -> agg1(+b1,relu)
//              -> GEMM2 -> agg2(+b2). Intermediates h/h1/h2 in bf16.
// agg kernels: wave-uniform node (readfirstlane) => scalar CSR loads, 8-deep gather MLP.

typedef __bf16 bf16x8 __attribute__((ext_vector_type(8)));
typedef float floatx4 __attribute__((ext_vector_type(4)));

__device__ inline unsigned short f2bf(float f) {      // RNE fp32->bf16
    unsigned u = __float_as_uint(f);
    u += 0x7FFF + ((u >> 16) & 1);
    return (unsigned short)(u >> 16);
}
__device__ inline float bflo(unsigned p) { return __uint_as_float(p << 16); }
__device__ inline float bfhi(unsigned p) { return __uint_as_float(p & 0xFFFF0000u); }

// ---------------- degree histogram ----------------
__global__ void k_deg(const int* __restrict__ dst, int* __restrict__ deg, int E) {
    int e = blockIdx.x * blockDim.x + threadIdx.x;
    if (e < E) atomicAdd(&deg[dst[e]], 1);
}

// ---------------- isd + offsets (wave scan + 1 atomic/wave) ----------------
__global__ void k_isd_offsets(const int* __restrict__ deg, float* __restrict__ isd,
                              int* __restrict__ offsets, int* __restrict__ counter, int N) {
    int n = blockIdx.x * blockDim.x + threadIdx.x;
    int lane = threadIdx.x & 63;
    int d = (n < N) ? deg[n] : 0;
    if (n < N) isd[n] = (d > 0) ? rsqrtf((float)d) : 0.f;
    int pref = d;
    #pragma unroll
    for (int sh = 1; sh < 64; sh <<= 1) {
        int t = __shfl_up(pref, sh);
        if (lane >= sh) pref += t;
    }
    int total = __shfl(pref, 63);
    int base = 0;
    if (lane == 63) base = atomicAdd(counter, total);
    base = __shfl(base, 63);
    if (n < N) offsets[n] = base + pref - d;
}

// ---------------- CSR scatter: interleaved {src, w_bits} ----------------
__global__ void k_scatter(const int* __restrict__ src, const int* __restrict__ dst,
                          const float* __restrict__ isd, const int* __restrict__ offsets,
                          int* __restrict__ cursor, int2* __restrict__ csr, int E) {
    int e = blockIdx.x * blockDim.x + threadIdx.x;
    if (e >= E) return;
    int d = dst[e];
    int s = src[e];
    int pos = atomicAdd(&cursor[d], 1);
    int2 rec;
    rec.x = s;
    rec.y = __float_as_int(isd[s] * isd[d]);
    csr[offsets[d] + pos] = rec;
}

// ---------------- W1 -> bf16, MFMA B-fragment order ----------------
__global__ void k_prep_w1(const float* __restrict__ W1, unsigned short* __restrict__ w1s) {
    int flat = blockIdx.x * 256 + threadIdx.x;   // 0..4095
    int kt = flat >> 9;
    int nt = (flat >> 6) & 7;
    int lane = flat & 63;
    int kbase = kt * 32 + ((lane >> 4) << 3);
    int n = nt * 16 + (lane & 15);
    unsigned short v[8];
    #pragma unroll
    for (int j = 0; j < 8; ++j) v[j] = f2bf(W1[(size_t)(kbase + j) * 128 + n]);
    unsigned short* d = &w1s[(size_t)flat * 8];
    *(short4*)(d)     = make_short4(v[0], v[1], v[2], v[3]);
    *(short4*)(d + 4) = make_short4(v[4], v[5], v[6], v[7]);
}

// ---------------- GEMM1: h[N,128](bf16) = x[N,256] @ W1 , MFMA 16x16x32 ----------------
__global__ __launch_bounds__(256) void k_gemm1(const float* __restrict__ X,
                                               const unsigned short* __restrict__ w1s,
                                               unsigned short* __restrict__ H, int N) {
    __shared__ __align__(16) unsigned short smem[8192];
    unsigned short* sA = smem;            // 4 mt * 64 lanes * 8
    unsigned short* sB = smem + 2048;     // 8 nt * 64 lanes * 8
    int tid = threadIdx.x;
    int lane = tid & 63;
    int wave = tid >> 6;
    int wr = wave >> 1;
    int wc = wave & 1;
    int m0 = blockIdx.x * 64;

    floatx4 acc[2][4] = {};

    for (int kt = 0; kt < 8; ++kt) {
        #pragma unroll
        for (int i = 0; i < 2; ++i) {
            int f = tid * 2 + i;
            int row = f >> 3;
            int c4 = (f & 7) * 4;
            float4 v = make_float4(0.f, 0.f, 0.f, 0.f);
            int grow = m0 + row;
            if (grow < N) v = *(const float4*)&X[(size_t)grow * 256 + kt * 32 + c4];
            int mt = row >> 4;
            int flane = (row & 15) | ((c4 >> 3) << 4);
            int j0 = c4 & 7;
            unsigned short* d = &sA[(size_t)(mt * 64 + flane) * 8 + j0];
            *(short4*)d = make_short4(f2bf(v.x), f2bf(v.y), f2bf(v.z), f2bf(v.w));
        }
        {
            const float4* srcp = (const float4*)&w1s[(size_t)kt * 4096];
            float4* dstp = (float4*)sB;
            dstp[tid] = srcp[tid];
            dstp[tid + 256] = srcp[tid + 256];
        }
        __syncthreads();
        bf16x8 a[2], b[4];
        #pragma unroll
        for (int p = 0; p < 2; ++p)
            a[p] = *(const bf16x8*)&sA[(size_t)((wr * 2 + p) * 64 + lane) * 8];
        #pragma unroll
        for (int q = 0; q < 4; ++q)
            b[q] = *(const bf16x8*)&sB[(size_t)((wc * 4 + q) * 64 + lane) * 8];
        #pragma unroll
        for (int p = 0; p < 2; ++p)
            #pragma unroll
            for (int q = 0; q < 4; ++q)
                acc[p][q] = __builtin_amdgcn_mfma_f32_16x16x32_bf16(a[p], b[q], acc[p][q], 0, 0, 0);
        __syncthreads();
    }
    #pragma unroll
    for (int p = 0; p < 2; ++p)
        #pragma unroll
        for (int q = 0; q < 4; ++q)
            #pragma unroll
            for (int r = 0; r < 4; ++r) {
                int rl = wr * 32 + p * 16 + ((lane >> 4) << 2) + r;
                int c = wc * 64 + q * 16 + (lane & 15);
                smem[rl * 128 + c] = f2bf(acc[p][q][r]);
            }
    __syncthreads();
    #pragma unroll
    for (int i = 0; i < 4; ++i) {
        int f = tid + i * 256;
        int row = f >> 4;
        int c8 = (f & 15) * 8;
        int grow = m0 + row;
        if (grow < N)
            *(float4*)&H[(size_t)grow * 128 + c8] = *(const float4*)&smem[row * 128 + c8];
    }
}

// ---------------- agg1: h1(bf16) = relu(b1 + sum w*h[src]) , C=128 ----------------
// wave/node; node scalarized => csr reads are s_loads; 8 gathers in flight
__global__ __launch_bounds__(256) void k_agg1(const unsigned* __restrict__ Hu,
                                              const int2* __restrict__ csr,
                                              const int* __restrict__ offsets,
                                              const int* __restrict__ deg,
                                              const float* __restrict__ b1,
                                              unsigned* __restrict__ H1u, int N) {
    int node = __builtin_amdgcn_readfirstlane((blockIdx.x * blockDim.x + threadIdx.x) >> 6);
    int lane = threadIdx.x & 63;
    if (node >= N) return;
    int start = offsets[node];
    int cnt = deg[node];
    float acc0 = 0.f, acc1 = 0.f;
    int i = 0;
    for (; i + 8 <= cnt; i += 8) {
        int2 e[8];
        #pragma unroll
        for (int j = 0; j < 8; ++j) e[j] = csr[start + i + j];      // scalar loads
        unsigned p[8];
        #pragma unroll
        for (int j = 0; j < 8; ++j) p[j] = Hu[(size_t)e[j].x * 64 + lane];  // 8 in flight
        #pragma unroll
        for (int j = 0; j < 8; ++j) {
            float w = __int_as_float(e[j].y);
            acc0 = fmaf(w, bflo(p[j]), acc0);
            acc1 = fmaf(w, bfhi(p[j]), acc1);
        }
    }
    for (; i < cnt; ++i) {
        int2 e = csr[start + i];
        unsigned p = Hu[(size_t)e.x * 64 + lane];
        float w = __int_as_float(e.y);
        acc0 = fmaf(w, bflo(p), acc0);
        acc1 = fmaf(w, bfhi(p), acc1);
    }
    float r0 = fmaxf(acc0 + b1[2 * lane], 0.f);
    float r1 = fmaxf(acc1 + b1[2 * lane + 1], 0.f);
    H1u[(size_t)node * 64 + lane] = (unsigned)f2bf(r0) | ((unsigned)f2bf(r1) << 16);
}

// ---------------- GEMM2: h2[N,40](bf16) = h1(bf16) @ W2[128,40] ----------------
__global__ __launch_bounds__(256) void k_gemm2(const unsigned short* __restrict__ H1,
                                               const float* __restrict__ W2,
                                               unsigned short* __restrict__ H2, int N) {
    __shared__ float sH[64][132];
    __shared__ float sW[128 * 40];
    int tid = threadIdx.x;
    int block_row = blockIdx.x * 64;
    for (int i = tid; i < 64 * 16; i += 256) {
        int r = i >> 4;
        int c8 = (i & 15) * 8;
        int grow = block_row + r;
        uint4 v = make_uint4(0, 0, 0, 0);
        if (grow < N) v = *(const uint4*)&H1[(size_t)grow * 128 + c8];
        float* d = &sH[r][c8];
        d[0] = bflo(v.x); d[1] = bfhi(v.x);
        d[2] = bflo(v.y); d[3] = bfhi(v.y);
        d[4] = bflo(v.z); d[5] = bfhi(v.z);
        d[6] = bflo(v.w); d[7] = bfhi(v.w);
    }
    for (int i = tid; i < 1280; i += 256)
        *(float4*)&sW[i * 4] = *(const float4*)&W2[(size_t)i * 4];
    __syncthreads();

    int row = tid >> 2;
    int c0 = (tid & 3) * 10;
    float acc[10] = {};
    for (int k = 0; k < 128; ++k) {
        float hv = sH[row][k];
        #pragma unroll
        for (int j = 0; j < 5; ++j) {
            float2 wv = *(const float2*)&sW[k * 40 + c0 + 2 * j];
            acc[2 * j]     = fmaf(hv, wv.x, acc[2 * j]);
            acc[2 * j + 1] = fmaf(hv, wv.y, acc[2 * j + 1]);
        }
    }
    int grow = block_row + row;
    if (grow < N) {
        unsigned* o = (unsigned*)&H2[(size_t)grow * 40 + c0];
        #pragma unroll
        for (int j = 0; j < 5; ++j)
            o[j] = (unsigned)f2bf(acc[2 * j]) | ((unsigned)f2bf(acc[2 * j + 1]) << 16);
    }
}

// ---------------- agg2: out[n][c](fp32) = b2 + sum w*h2[src] , C=40 ----------------
// lane = 20*g + c : 3 edge-groups in parallel, cross-group shfl reduce at end
__global__ __launch_bounds__(256) void k_agg2(const unsigned* __restrict__ Hu,
                                              const int2* __restrict__ csr,
                                              const int* __restrict__ offsets,
                                              const int* __restrict__ deg,
                                              const float* __restrict__ b2,
                                              float* __restrict__ out, int N) {
    int node = __builtin_amdgcn_readfirstlane((blockIdx.x * blockDim.x + threadIdx.x) >> 6);
    int lane = threadIdx.x & 63;
    if (node >= N) return;
    int start = offsets[node];
    int cnt = deg[node];
    int g = lane / 20;         // 0..3 (g==3 idle)
    int c = lane % 20;
    bool active = g < 3;
    float acc0 = 0.f, acc1 = 0.f;
    for (int i0 = 0; i0 < cnt; i0 += 12) {
        #pragma unroll
        for (int j = 0; j < 4; ++j) {
            int e = i0 + j * 3 + g;
            if (active && e < cnt) {
                int2 r = csr[start + e];
                unsigned p = Hu[(size_t)r.x * 20 + c];
                float w = __int_as_float(r.y);
                acc0 = fmaf(w, bflo(p), acc0);
                acc1 = fmaf(w, bfhi(p), acc1);
            }
        }
    }
    // sum groups 0+1+2 (valid on lanes 0..19)
    float t0 = __shfl(acc0, (lane + 20) & 63) + __shfl(acc0, (lane + 40) & 63);
    float t1 = __shfl(acc1, (lane + 20) & 63) + __shfl(acc1, (lane + 40) & 63);
    acc0 += t0;
    acc1 += t1;
    if (lane < 20)
        *(float2*)&out[(size_t)node * 40 + 2 * lane] =
            make_float2(acc0 + b2[2 * lane], acc1 + b2[2 * lane + 1]);
}

extern "C" void kernel_launch(void* const* d_in, const int* in_sizes, int n_in,
                              void* d_out, int out_size, void* d_ws, size_t ws_size,
                              hipStream_t stream) {
    const float* x  = (const float*)d_in[0];
    const int*  src = (const int*)d_in[1];
    const int*  dst = (const int*)d_in[2];
    const float* W1 = (const float*)d_in[3];
    const float* b1 = (const float*)d_in[4];
    const float* W2 = (const float*)d_in[5];
    const float* b2 = (const float*)d_in[6];
    float* out = (float*)d_out;

    const int N = in_sizes[0] / 256;   // 100000
    const int E = in_sizes[1];         // 1600000

    char* w = (char*)d_ws;
    auto alloc = [&](size_t bytes) -> void* {
        void* p = (void*)w;
        w += (bytes + 15) & ~(size_t)15;
        return p;
    };
    int*   deg     = (int*)alloc((size_t)N * 4);      // zeroed below
    int*   cursor  = (int*)alloc((size_t)N * 4);      // zeroed below
    int*   counter = (int*)alloc(16);                 // zeroed below
    float* isd     = (float*)alloc((size_t)N * 4);
    int*   offsets = (int*)alloc((size_t)N * 4);
    int2*  csr     = (int2*)alloc((size_t)E * 8);
    unsigned short* w1s = (unsigned short*)alloc(32768 * 2);
    unsigned short* h   = (unsigned short*)alloc((size_t)N * 128 * 2);
    unsigned short* h1  = (unsigned short*)alloc((size_t)N * 128 * 2);
    unsigned short* h2  = h;   // h dead after agg1

    hipMemsetAsync(deg, 0, (size_t)N * 4 * 2 + 16, stream);

    k_deg<<<(E + 255) / 256, 256, 0, stream>>>(dst, deg, E);
    k_isd_offsets<<<(N + 255) / 256, 256, 0, stream>>>(deg, isd, offsets, counter, N);
    k_scatter<<<(E + 255) / 256, 256, 0, stream>>>(src, dst, isd, offsets, cursor, csr, E);
    k_prep_w1<<<16, 256, 0, stream>>>(W1, w1s);
    k_gemm1<<<(N + 63) / 64, 256, 0, stream>>>(x, w1s, h, N);
    k_agg1<<<(N + 3) / 4, 256, 0, stream>>>((const unsigned*)h, csr, offsets, deg, b1,
                                            (unsigned*)h1, N);
    k_gemm2<<<(N + 63) / 64, 256, 0, stream>>>(h1, W2, h2, N);
    k_agg2<<<(N + 3) / 4, 256, 0, stream>>>((const unsigned*)h2, csr, offsets, deg, b2,
                                            out, N);
}